// Round 7
// baseline (418.631 us; speedup 1.0000x reference)
//
#include <hip/hip_runtime.h>
#include <math.h>

typedef unsigned long long u64;
typedef unsigned int u32;

static constexpr int S    = 771;   // NB_LABELS*MAX_DEPTH + EXTRA
static constexpr int Tn   = 128;
static constexpr int Bn   = 32;
static constexpr int BOSs = 0;
static constexpr int EOSs = 1;

// r16 geometry (= r13): 2 blocks x 448 rows per batch, 512 threads (8 waves).
static constexpr int NB    = 2;            // blocks per batch (grid.y)
static constexpr int ROWS  = 448;          // output rows per block
static constexpr int JPAD  = NB * ROWS;    // 896 padded states
static constexpr int NW    = 8;            // waves per block
static constexpr int KSEG  = JPAD / NW;    // 112 i8 inner per wave K-segment
static constexpr int KKN   = KSEG / 16;    // 7 uint4 per K-segment
static constexpr int RPL   = 7;            // rows per lane in the dot
static constexpr int EPW   = 56;           // rows per wave in the epilogue
static constexpr int WPW   = 14;           // data words per wave publish
static constexpr int NDATA = JPAD / 4;     // 224 tagged data words per gen
static constexpr int XSTR  = 256;          // u64 stride per (parity,batch)
static constexpr int EBLK  = NW * 64 * 49 * 16;   // 401408 B per jb
static constexpr int ETOT  = NB * EBLK;           // 802816 B
static constexpr float CB  = 8.0f;         // normalizer headroom (drift bound)
static constexpr float C0V = 4.5f;         // fixed normalizer for t=0 publish

__device__ __forceinline__ float wave_max_bfly(float v) {   // result in ALL lanes
    #pragma unroll
    for (int off = 32; off > 0; off >>= 1) v = fmaxf(v, __shfl_xor(v, off));
    return v;
}
__device__ __forceinline__ float wave_sum_f(float v) {
    #pragma unroll
    for (int off = 32; off > 0; off >>= 1) v += __shfl_down(v, off);
    return v;
}

__device__ __forceinline__ u64 ald64(const u64* p) {
    return __hip_atomic_load((u64*)p, __ATOMIC_RELAXED, __HIP_MEMORY_SCOPE_AGENT);
}
__device__ __forceinline__ void ast64(u64* p, u64 v) {
    __hip_atomic_store(p, v, __ATOMIC_RELAXED, __HIP_MEMORY_SCOPE_AGENT);
}
__device__ __forceinline__ u64 pack(unsigned tag, unsigned payload) {
    return ((u64)tag << 32) | (u64)payload;
}

// i8 x i8 + i32 dot (both operands in [0,127], so signed == unsigned)
#if __has_builtin(__builtin_amdgcn_sdot4)
__device__ __forceinline__ int dot4i(unsigned a, unsigned b, int c) {
    return __builtin_amdgcn_sdot4((int)a, (int)b, c, false);
}
#else
__device__ __forceinline__ int dot4i(unsigned a, unsigned b, int c) {
    c += (int)(a & 0xff)         * (int)(b & 0xff);
    c += (int)((a >> 8) & 0xff)  * (int)((b >> 8) & 0xff);
    c += (int)((a >> 16) & 0xff) * (int)((b >> 16) & 0xff);
    c += (int)((a >> 24) & 0xff) * (int)((b >> 24) & 0xff);
    return c;
}
#endif

// ---------------------------------------------------------------------------
// Prep (r13 layout, unchanged): i8 exp-transition table for REGISTER-resident
// full-K E. uint4 index (((jb*8 + w)*49 + (i*7 + kk))*64 + lane) holds 16 i8:
//   k = w*112 + kk*16 + e        (inner state: wave w's K-segment)
//   j = jb*448 + lane*7 + i      (output row; lane owns 7 dot-rows)
// value = round(115*exp(trans[k][j])) in [0,127].
// ---------------------------------------------------------------------------
extern "C" __global__ void build_tabs(const float* __restrict__ trans,
                                      unsigned char* __restrict__ eswz,
                                      float* __restrict__ eteos) {
    int idx = blockIdx.x * blockDim.x + threadIdx.x;
    if (idx < JPAD)
        eteos[idx] = (idx < S) ? __expf(trans[idx * S + EOSs]) : 0.f;
    if (idx >= ETOT) return;
    int e = idx & 15;
    int u = idx >> 4;
    int lane = u & 63;  u >>= 6;
    int kk = u % 7;     u /= 7;
    int i  = u % 7;     u /= 7;
    int w  = u & 7;
    int jb = u >> 3;
    int k = w * KSEG + kk * 16 + e;
    int j = jb * ROWS + lane * RPL + i;
    float v = 0.f;
    if (k < S && j < S) v = 115.f * __expf(trans[k * S + j]);
    int q8 = (int)(v + 0.5f);
    if (q8 > 127) q8 = 127;
    eswz[idx] = (unsigned char)q8;
}

// ---------------------------------------------------------------------------
// Forward algorithm, r16 = r13 + CORRECT REGISTER BUDGET.
// r13 post-mortem: __launch_bounds__(512, 2) demanded 2 blocks/CU = 4
// waves/SIMD = a 128-VGPR CAP, while the kernel requests 196 VGPRs of E per
// thread -> ~70 VGPRs/thread spilled to scratch, and the dot re-read ~400KB
// of E from SCRATCH every step. r13's 361us measured spill traffic, not the
// structure. Fix (single variable): __launch_bounds__(512) +
// amdgpu_waves_per_eu(2,2) -> exactly 2 waves/SIMD -> 256-VGPR budget ->
// E (196) + working (~40) fits. Tripwire: VGPR_Count ~230-256, scratch 0.
// Structure (unchanged from r13):
//  - Block jb owns rows [448jb, 448jb+448); E in registers; zero E traffic.
//  - Wave w = K-segment [112w,112w+112) for its lanes' 7 rows; partials
//    combined through LDS (barrier B).
//  - OWN alpha-half through LDS; only REMOTE half polled: wave w polls the
//    corresponding remote wave's 14 data words + 1 max word (ONE remote
//    poller per word); barrier A completes strip[p_r].
//  - grid dim3(Bn, NB): batch pair 32 apart -> same XCD (incidental).
// Sync safety: per-word tags; all 240 remote words of gen t-1 consumed (via
// the 8 waves + barrier A) before the gen-t publish -> r8 transitivity
// holds. Numerics identical to r12/r13 (quant, CB, C0V, p8, max channel).
// ---------------------------------------------------------------------------
extern "C" __global__ __attribute__((amdgpu_waves_per_eu(2, 2)))
__launch_bounds__(512)
void crf_fwd(const float* __restrict__ em, const float* __restrict__ mask,
             const float* __restrict__ trans, const int* __restrict__ tags,
             const unsigned char* __restrict__ eswz,
             const float* __restrict__ eteos,
             u64* __restrict__ xb, float* __restrict__ out) {
    const int b = blockIdx.x, jb = blockIdx.y;
    const int tid = threadIdx.x, lane = tid & 63, w = tid >> 6;

    __shared__ __align__(16) u32 strip[2][NDATA];     // full p8 alpha, by parity
    __shared__ int   part[NW][ROWS + 8];              // K-segment partials
    __shared__ float mredR[2][NW], mredL[2][NW];      // remote/local wave maxes
    __shared__ float redv[NW], redm[NW], redl[NW];

    const float KLOG  = __logf(115.f * 127.f);
    const float KL127 = __logf(127.f);

    // epilogue row of this thread: block-local erow, global j
    const int erow = EPW * w + lane;                  // valid for lane < 56
    const int j    = jb * ROWS + erow;
    const bool ownr = (lane < EPW) && (j < S);

    // ---- t=0: alpha0, publish gen 0 (+ own strip half + local maxes) ----
    float af = -INFINITY, Cuse = C0V;
    if (ownr) af = trans[BOSs * S + j] + em[((size_t)b * Tn + 0) * S + j];
    {
        u64* Wp = xb + ((size_t)0 * Bn + b) * XSTR;
        float xf = fminf(127.f, 127.f * __expf(af - C0V));
        int xi = (int)(xf + 0.5f);
        int b0 = __shfl(xi, (4 * lane) & 63);
        int b1 = __shfl(xi, (4 * lane + 1) & 63);
        int b2 = __shfl(xi, (4 * lane + 2) & 63);
        int b3 = __shfl(xi, (4 * lane + 3) & 63);
        unsigned payload = (unsigned)b0 | ((unsigned)b1 << 8)
                         | ((unsigned)b2 << 16) | ((unsigned)b3 << 24);
        float wmax = wave_max_bfly(af);
        if (lane < WPW) {
            ast64(Wp + WPW * NW * jb + WPW * w + lane, pack(0u, payload));
            strip[0][WPW * NW * jb + WPW * w + lane] = payload;
        }
        if (lane == WPW)     ast64(Wp + NDATA + NW * jb + w, pack(0u, __float_as_uint(wmax)));
        if (lane == WPW + 1) mredL[0][w] = wmax;
    }

    // ---- E into registers: 7 rows x 7 uint4 = 49 uint4 = 196 VGPR ----
    uint4 ereg[RPL][KKN];
    {
        const uint4* esrc = (const uint4*)eswz
                          + ((size_t)(jb * NW + w) * 49) * 64 + lane;
        #pragma unroll
        for (int i = 0; i < RPL; ++i)
            #pragma unroll
            for (int kk = 0; kk < KKN; ++kk)
                ereg[i][kk] = esrc[(i * 7 + kk) * 64];
    }
    // opaque pin: force residency, forbid sinking the loads into the loop
    #pragma unroll
    for (int i = 0; i < RPL; ++i)
        #pragma unroll
        for (int kk = 0; kk < KKN; ++kk)
            asm volatile("" : "+v"(ereg[i][kk].x), "+v"(ereg[i][kk].y),
                              "+v"(ereg[i][kk].z), "+v"(ereg[i][kk].w));

    const int o = 1 - jb;                             // remote block
    const bool pact = (lane < WPW + 1);               // 14 data + 1 max poller

    // ---- 127 sequential steps, two barriers each ----
    for (int t = 1; t < Tn; ++t) {
        const int p_r = (t - 1) & 1, p_w = t & 1;
        const u64* R  = xb + ((size_t)p_r * Bn + b) * XSTR;
        u64*       Wp = xb + ((size_t)p_w * Bn + b) * XSTR;

        // epilogue operands independent of alpha: issue before the poll
        float emv = 0.f;
        if (ownr) emv = em[((size_t)b * Tn + t) * S + j];
        float mval = mask[b * Tn + t];

        // ---- poll the REMOTE half: one word per lane, 2-deep pipelined ----
        const unsigned tg = (unsigned)(t - 1);
        const u64* pp = (lane < WPW)
                      ? (R + WPW * NW * o + WPW * w + lane)
                      : (R + NDATA + NW * o + w);
        u64 qc = 0, qn = 0;
        bool ok = !pact;
        if (pact) { qc = ald64(pp); qn = qc; }
        while (true) {
            if (!ok) { if ((u32)(qc >> 32) == tg) ok = true; else qc = qn; }
            if (!__any(!ok)) break;
            if (!ok) qn = ald64(pp);
        }
        if (lane < WPW)  strip[p_r][WPW * NW * o + WPW * w + lane] = (u32)qc;
        if (lane == WPW) mredR[p_r][w] = __uint_as_float((u32)qc);

        __syncthreads();   // barrier A: strip[p_r] complete (own + remote)

        // ---- dot: in-register E x K-segment strip (b128 broadcast) ----
        int acc[RPL];
        #pragma unroll
        for (int i = 0; i < RPL; ++i) acc[i] = 0;
        const uint4* P4 = (const uint4*)(&strip[p_r][0]) + KKN * w;
        #pragma unroll
        for (int kk = 0; kk < KKN; ++kk) {
            const uint4 pv = P4[kk];
            #pragma unroll
            for (int i = 0; i < RPL; ++i) {
                acc[i] = dot4i(ereg[i][kk].x, pv.x, acc[i]);
                acc[i] = dot4i(ereg[i][kk].y, pv.y, acc[i]);
                acc[i] = dot4i(ereg[i][kk].z, pv.z, acc[i]);
                acc[i] = dot4i(ereg[i][kk].w, pv.w, acc[i]);
            }
        }
        #pragma unroll
        for (int i = 0; i < RPL; ++i) part[w][RPL * lane + i] = acc[i];

        __syncthreads();   // barrier B: partials complete

        // ---- epilogue: combine 8 K-segments for own row, publish gen t ----
        int s4 = 0;
        #pragma unroll
        for (int ws = 0; ws < NW; ++ws) s4 += part[ws][erow];
        float cm = -INFINITY;
        #pragma unroll
        for (int k2 = 0; k2 < NW; ++k2)
            cm = fmaxf(cm, fmaxf(mredR[p_r][k2], mredL[p_r][k2]));
        float Cnew = cm + CB;
        float nv = Cuse - KLOG + __logf((float)s4) + emv;  // log(0) = -inf
        if (lane < EPW) af = (mval > 0.f) ? nv : af;

        float xf = fminf(127.f, 127.f * __expf(af - Cnew));
        int xi = (int)(xf + 0.5f);
        int b0 = __shfl(xi, (4 * lane) & 63);
        int b1 = __shfl(xi, (4 * lane + 1) & 63);
        int b2 = __shfl(xi, (4 * lane + 2) & 63);
        int b3 = __shfl(xi, (4 * lane + 3) & 63);
        unsigned payload = (unsigned)b0 | ((unsigned)b1 << 8)
                         | ((unsigned)b2 << 16) | ((unsigned)b3 << 24);
        float wmax = wave_max_bfly(af);
        if (lane < WPW) {
            ast64(Wp + WPW * NW * jb + WPW * w + lane, pack((unsigned)t, payload));
            strip[p_w][WPW * NW * jb + WPW * w + lane] = payload;
        }
        if (lane == WPW)     ast64(Wp + NDATA + NW * jb + w, pack((unsigned)t, __float_as_uint(wmax)));
        if (lane == WPW + 1) mredL[p_w][w] = wmax;
        Cuse = Cnew;
    }

    // ---- tail (blocks jb==0 only): log_Z + gold score + output ----
    if (jb == 0) {
        const u64* R = xb + ((size_t)((Tn - 1) & 1) * Bn + b) * XSTR;
        const unsigned tg = (unsigned)(Tn - 1);
        const bool tact = (tid < NDATA);
        u64 qd = 0;
        bool ok = !tact;
        while (true) {
            if (!ok) { qd = ald64(R + tid); ok = ((u32)(qd >> 32) == tg); }
            if (__syncthreads_and(ok)) break;
        }
        float lsum = 0.f;
        if (tact) {
            unsigned pv = (unsigned)qd;
            int base = 4 * tid;               // p8 index j = 4*word + e
            lsum = (float)(pv & 0xff)         * eteos[base]
                 + (float)((pv >> 8)  & 0xff) * eteos[base + 1]
                 + (float)((pv >> 16) & 0xff) * eteos[base + 2]
                 + (float)((pv >> 24) & 0xff) * eteos[base + 3];
        }
        // gold-path score: thread tid<128 handles position tid
        float mk = 0.f, val = 0.f;
        if (tid < Tn) {
            mk = mask[b * Tn + tid];
            if (tid > 0) {
                int cur  = tags[b * Tn + tid];
                int prev = tags[b * Tn + tid - 1];
                val = (em[((size_t)b * Tn + tid) * S + cur]
                       + trans[prev * S + cur]) * mk;
            }
        }
        lsum = wave_sum_f(lsum);
        float vs = wave_sum_f(val);
        float ms = wave_sum_f(mk);
        if (lane == 0) { redv[w] = vs; redm[w] = ms; }
        if (lane == 1) redl[w] = lsum;
        __syncthreads();
        if (tid == 0) {
            float tot = 0.f, msum = 0.f, vsum = 0.f;
            #pragma unroll
            for (int k2 = 0; k2 < NW; ++k2) {
                tot += redl[k2]; msum += redm[k2]; vsum += redv[k2];
            }
            float logz = Cuse - KL127 + __logf(tot);   // Cuse = C of gen-127 publish
            int last   = (int)(msum + 0.5f) - 1;
            int first  = tags[b * Tn];
            int lastt  = tags[b * Tn + last];
            float score = vsum
                        + trans[BOSs * S + first]
                        + em[((size_t)b * Tn) * S + first]
                        + trans[lastt * S + EOSs];
            atomicAdd(out, -(score - logz));
        }
    }
}

extern "C" void kernel_launch(void* const* d_in, const int* in_sizes, int n_in,
                              void* d_out, int out_size, void* d_ws, size_t ws_size,
                              hipStream_t stream) {
    const float* em    = (const float*)d_in[0];
    const int*   tags  = (const int*)d_in[1];
    const float* mask  = (const float*)d_in[2];
    const float* trans = (const float*)d_in[3];
    float* out = (float*)d_out;

    char* ws = (char*)d_ws;
    size_t off = 0;
    unsigned char* eswz = (unsigned char*)(ws + off);
    off += (size_t)ETOT;
    off = (off + 255) & ~(size_t)255;
    float* eteos = (float*)(ws + off); off += JPAD * sizeof(float);
    off = (off + 255) & ~(size_t)255;
    u64* xb = (u64*)(ws + off);        off += (size_t)2 * Bn * XSTR * sizeof(u64);

    // ws re-poisoned 0xAA pre-launch: stale tags (0xAAAAAAAA) never match t<128
    (void)hipMemsetAsync(out, 0, sizeof(float), stream);

    build_tabs<<<(ETOT + 255) / 256, 256, 0, stream>>>(trans, eswz, eteos);
    crf_fwd<<<dim3(Bn, NB), 512, 0, stream>>>(em, mask, trans, tags, eswz,
                                              eteos, xb, out);
}

// Round 8
// 386.570 us; speedup vs baseline: 1.0829x; 1.0829x over previous
//
#include <hip/hip_runtime.h>
#include <math.h>

typedef unsigned long long u64;
typedef unsigned int u32;

static constexpr int S    = 771;   // NB_LABELS*MAX_DEPTH + EXTRA
static constexpr int Tn   = 128;
static constexpr int Bn   = 32;
static constexpr int BOSs = 0;
static constexpr int EOSs = 1;

// r12 geometry (best, 299us): 7 blocks x 128 rows per batch, 224 blocks.
static constexpr int JB    = 7;            // state-blocks per batch (grid.x)
static constexpr int ROWS  = 128;          // output rows per block
static constexpr int JPAD  = JB * ROWS;    // 896 padded states
static constexpr int NW    = 4;            // waves per block (K-quarters)
static constexpr int KQ    = JPAD / NW;    // 224 i8 inner slice per wave
static constexpr int KW    = KQ / 4;       // 56 u32 words per quarter
static constexpr int KK    = KQ / 16;      // 14 uint4 per row-quarter
static constexpr int NDATA = JPAD / 4;     // 224 tagged data words per gen
static constexpr int NMAX  = JB * NW;      // 28 tagged per-wave max words
static constexpr int XSTR  = 256;          // u64 stride per (parity,batch)
static constexpr int EBLK  = NW * KK * 2 * 64 * 16;  // 114688 B per jblk
static constexpr int ETOT  = JB * EBLK;              // 802816 B
static constexpr float CB  = 8.0f;         // normalizer headroom (drift bound)
static constexpr float C0V = 4.5f;         // fixed normalizer for t=0 publish

__device__ __forceinline__ float wave_max_bfly(float v) {   // result in ALL lanes
    #pragma unroll
    for (int off = 32; off > 0; off >>= 1) v = fmaxf(v, __shfl_xor(v, off));
    return v;
}
__device__ __forceinline__ float wave_sum_f(float v) {
    #pragma unroll
    for (int off = 32; off > 0; off >>= 1) v += __shfl_down(v, off);
    return v;
}

__device__ __forceinline__ u64 ald64(const u64* p) {
    return __hip_atomic_load((u64*)p, __ATOMIC_RELAXED, __HIP_MEMORY_SCOPE_AGENT);
}
__device__ __forceinline__ void ast64(u64* p, u64 v) {
    __hip_atomic_store(p, v, __ATOMIC_RELAXED, __HIP_MEMORY_SCOPE_AGENT);
}
__device__ __forceinline__ u64 pack(unsigned tag, unsigned payload) {
    return ((u64)tag << 32) | (u64)payload;
}

// i8 x i8 + i32 dot (both operands in [0,127], so signed == unsigned)
#if __has_builtin(__builtin_amdgcn_sdot4)
__device__ __forceinline__ int dot4i(unsigned a, unsigned b, int c) {
    return __builtin_amdgcn_sdot4((int)a, (int)b, c, false);
}
#else
__device__ __forceinline__ int dot4i(unsigned a, unsigned b, int c) {
    c += (int)(a & 0xff)         * (int)(b & 0xff);
    c += (int)((a >> 8) & 0xff)  * (int)((b >> 8) & 0xff);
    c += (int)((a >> 16) & 0xff) * (int)((b >> 16) & 0xff);
    c += (int)((a >> 24) & 0xff) * (int)((b >> 24) & 0xff);
    return c;
}
#endif

// ---------------------------------------------------------------------------
// Prep (r12 layout, unchanged): i8 exp-transition table.
// Linear u128 index (((jb*4 + w)*14 + kk)*2 + rr)*64 + lane holds 16 i8:
//   i = w*224 + kk*16 + e      (inner state: wave w's K-quarter)
//   j = jb*128 + rr*64 + lane  (output row; lane computes rows rr=0,1)
// value = round(115*exp(trans[i][j])) in [0,127].
// ---------------------------------------------------------------------------
extern "C" __global__ void build_tabs(const float* __restrict__ trans,
                                      unsigned char* __restrict__ eswz,
                                      float* __restrict__ eteos) {
    int idx = blockIdx.x * blockDim.x + threadIdx.x;
    if (idx < JPAD)
        eteos[idx] = (idx < S) ? __expf(trans[idx * S + EOSs]) : 0.f;
    if (idx >= ETOT) return;
    int e = idx & 15;
    int u = idx >> 4;
    int lane = u & 63;  u >>= 6;
    int rr = u & 1;     u >>= 1;
    int kk = u % KK;
    int h  = u / KK;
    int w  = h & 3, jb = h >> 2;
    int i = w * KQ + kk * 16 + e;
    int j = jb * ROWS + rr * 64 + lane;
    float v = 0.f;
    if (i < S && j < S) v = 115.f * __expf(trans[i * S + j]);
    int q8 = (int)(v + 0.5f);
    if (q8 > 127) q8 = 127;
    eswz[idx] = (unsigned char)q8;
}

// per-wave publish: wave w owns rows [32w, 32w+32) of its block (af in lanes
// 0..31). 8 data u64 (word 32jb+8w+k = rows 4k..4k+3 p8-packed) + 1 max u64
// (word NDATA + 4jb + w = wave max). Tag stream IS the sync.
__device__ __forceinline__ void publishW(u64* Wp, int jb, int w, unsigned tag,
                                         float af, float C, int lane) {
    float xf = fminf(127.f, 127.f * __expf(af - C));   // -inf/-1e9 -> 0
    int xi = (int)(xf + 0.5f);
    int b0 = __shfl(xi, (4 * lane) & 63);
    int b1 = __shfl(xi, (4 * lane + 1) & 63);
    int b2 = __shfl(xi, (4 * lane + 2) & 63);
    int b3 = __shfl(xi, (4 * lane + 3) & 63);
    unsigned payload = (unsigned)b0 | ((unsigned)b1 << 8)
                     | ((unsigned)b2 << 16) | ((unsigned)b3 << 24);
    float mc = wave_max_bfly(af);                      // lanes>=32 are -inf
    if (lane < 8)  ast64(Wp + 32 * jb + 8 * w + lane, pack(tag, payload));
    if (lane == 8) ast64(Wp + NDATA + 4 * jb + w,     pack(tag, __float_as_uint(mc)));
}

// ---------------------------------------------------------------------------
// Forward algorithm, r17 = r12 (299us best) + E RESIDENT IN LDS.
// Post-mortems r11/r13/r16: hipcc refuses to keep ~200 loop-carried VGPRs of
// E live across the spin+barrier loop (VGPR stuck at 84-132) -> r12 was
// re-streaming its 114KB E slice from L2 EVERY STEP, serially AFTER the poll
// (remat'd loads live inside the dot). Per-CU L1<->L2 BW (~64B/cy) makes
// that ~1800cy of the 5600cy step. Fix: EBLK = 114688 B FITS IN LDS (160KB;
// the 8-phase GEMM template uses 128KB/wg on gfx950). Stage once at start;
// the dot reads ds_read_b128 -> zero per-step E traffic, no VGPR pressure,
// no remat. Step chain becomes detect + LDS-dot(~1100cy, waves start as
// their own quarter's publishers arrive) + barrier + epilogue + publish.
// Tripwire: FETCH_SIZE must drop 42 -> ~17MB (E-stream leaves VMEM).
// Everything else bit-identical to r12 (poll, strip, part, publish, tail).
// ---------------------------------------------------------------------------
extern "C" __global__ __launch_bounds__(256, 1)
void crf_fwd(const float* __restrict__ em, const float* __restrict__ mask,
             const float* __restrict__ trans, const int* __restrict__ tags,
             const unsigned char* __restrict__ eswz,
             const float* __restrict__ eteos,
             u64* __restrict__ xb, float* __restrict__ out) {
    const int jb = blockIdx.x, b = blockIdx.y;
    const int tid = threadIdx.x, lane = tid & 63, w = tid >> 6;

    __shared__ __align__(16) unsigned char Elds[EBLK];  // 112 KB i8 E slice
    __shared__ __align__(16) u32 strip[NW * KW];        // per-wave quarter p8
    __shared__ int   part[2][NW][ROWS];
    __shared__ float mred[2][NW];
    __shared__ float cshare;
    __shared__ float redv[NW], redm[NW], redl[NW];

    const float KLOG  = __logf(115.f * 127.f);
    const float KL127 = __logf(127.f);

    // epilogue rows of this wave: lane l<32 owns row jb*128 + 32w + l
    const int jrow = jb * ROWS + 32 * w + lane;

    // ---- t=0: publish first (unblocks everyone), then stage E into LDS ----
    float af = -INFINITY, Cuse = C0V;
    if (lane < 32 && jrow < S)
        af = trans[BOSs * S + jrow] + em[((size_t)b * Tn + 0) * S + jrow];
    publishW(xb + ((size_t)0 * Bn + b) * XSTR, jb, w, 0u, af, C0V, lane);

    {   // one-time linear copy of this block's E slab (28 x 4KB)
        const unsigned char* gsrc = eswz + (size_t)jb * EBLK;
        #pragma unroll
        for (int it = 0; it < EBLK / 4096; ++it)
            *(float4*)(Elds + it * 4096 + tid * 16) =
                *(const float4*)(gsrc + it * 4096 + tid * 16);
    }
    __syncthreads();   // E staged before first dot

    const bool actd = (lane < KW);                     // 56 data-poll lanes
    const bool actm = (lane >= KW) && (lane < KW + 7); // 7 max-poll lanes

    // in-LDS E base for this wave's quarter: u4 index w*1792 + kk*128 + rr*64 + lane
    const uint4* E4 = (const uint4*)Elds + (size_t)w * (KK * 2 * 64) + lane;

    // ---- 127 sequential steps, one barrier each ----
    for (int t = 1; t < Tn; ++t) {
        const u64* R  = xb + ((size_t)((t - 1) & 1) * Bn + b) * XSTR;
        u64*       Wp = xb + ((size_t)((t    ) & 1) * Bn + b) * XSTR;

        // epilogue operands independent of alpha: issue before the poll
        float emv = 0.f;
        if (lane < 32 && jrow < S) emv = em[((size_t)b * Tn + t) * S + jrow];
        float mval = mask[b * Tn + t];

        // ---- pipelined poll: wave w waits only on its quarter's publishers
        const unsigned tg = (unsigned)(t - 1);
        const u64* pd = R + KW * w + lane;               // data word (lane<56)
        const u64* pm = R + NDATA + 7 * w + (lane - KW); // max word (7 lanes)
        u64 dc = 0, dn = 0, mc = 0, mn = 0;
        bool okd = !actd, okm = !actm;
        if (actd) { dc = ald64(pd); dn = dc; }
        if (actm) { mc = ald64(pm); mn = mc; }
        while (true) {
            if (!okd) { if ((u32)(dc >> 32) == tg) okd = true; else dc = dn; }
            if (!okm) { if ((u32)(mc >> 32) == tg) okm = true; else mc = mn; }
            if (!__any((!okd) | (!okm))) break;
            if (!okd) dn = ald64(pd);
            if (!okm) mn = ald64(pm);
        }

        // ---- own strip (same-wave DS write->read: in-order, no barrier) ----
        if (actd) strip[w * KW + lane] = (u32)dc;

        // per-wave partial of next normalizer (full max after the barrier)
        float pmv = actm ? __uint_as_float((u32)mc) : -INFINITY;
        float wmax = wave_max_bfly(pmv);
        if (lane == 0) mred[t & 1][w] = wmax;

        // ---- dot: LDS E (2 rows/lane, b128) x quarter strip (broadcast) ----
        int a0 = 0, a1 = 0;
        const uint4* P4 = (const uint4*)(strip + w * KW);
        #pragma unroll
        for (int kk = 0; kk < KK; ++kk) {
            const uint4 pv = P4[kk];
            const uint4 ev0 = E4[kk * 128];
            const uint4 ev1 = E4[kk * 128 + 64];
            a0 = dot4i(ev0.x, pv.x, a0);
            a0 = dot4i(ev0.y, pv.y, a0);
            a0 = dot4i(ev0.z, pv.z, a0);
            a0 = dot4i(ev0.w, pv.w, a0);
            a1 = dot4i(ev1.x, pv.x, a1);
            a1 = dot4i(ev1.y, pv.y, a1);
            a1 = dot4i(ev1.z, pv.z, a1);
            a1 = dot4i(ev1.w, pv.w, a1);
        }
        part[t & 1][w][lane]      = a0;
        part[t & 1][w][64 + lane] = a1;
        __syncthreads();   // the ONLY per-step barrier

        // ---- distributed epilogue: wave w finishes rows 32w..32w+31 ----
        const int p_ = t & 1;
        const int Rr = 32 * w + (lane & 31);
        int s4 = part[p_][0][Rr] + part[p_][1][Rr]
               + part[p_][2][Rr] + part[p_][3][Rr];
        float Cnew = fmaxf(fmaxf(mred[p_][0], mred[p_][1]),
                           fmaxf(mred[p_][2], mred[p_][3])) + CB;
        float nv = Cuse - KLOG + __logf((float)s4) + emv;  // log(0) = -inf
        if (lane < 32) af = (mval > 0.f) ? nv : af;
        publishW(Wp, jb, w, (unsigned)t, af, Cnew, lane);
        Cuse = Cnew;
    }

    if (w == 0 && lane == 0) cshare = Cuse;   // C of the gen-127 publish

    // ---- tail (blocks jb==0 only): log_Z + gold score + output ----
    if (jb == 0) {
        const u64* R = xb + ((size_t)((Tn - 1) & 1) * Bn + b) * XSTR;
        const unsigned tg = (unsigned)(Tn - 1);
        const bool tact = (tid < NDATA);
        u64 qd = 0;
        bool ok = !tact;
        while (true) {
            if (!ok) { qd = ald64(R + tid); ok = ((u32)(qd >> 32) == tg); }
            if (__syncthreads_and(ok)) break;
        }
        float lsum = 0.f;
        if (tact) {
            unsigned pv = (unsigned)qd;
            int base = 4 * tid;               // p8 index j = 4*word + e
            lsum = (float)(pv & 0xff)         * eteos[base]
                 + (float)((pv >> 8)  & 0xff) * eteos[base + 1]
                 + (float)((pv >> 16) & 0xff) * eteos[base + 2]
                 + (float)((pv >> 24) & 0xff) * eteos[base + 3];
        }
        // gold-path score: thread tid<128 handles position tid
        float mk = 0.f, val = 0.f;
        if (tid < Tn) {
            mk = mask[b * Tn + tid];
            if (tid > 0) {
                int cur  = tags[b * Tn + tid];
                int prev = tags[b * Tn + tid - 1];
                val = (em[((size_t)b * Tn + tid) * S + cur]
                       + trans[prev * S + cur]) * mk;
            }
        }
        lsum = wave_sum_f(lsum);
        float vs = wave_sum_f(val);
        float ms = wave_sum_f(mk);
        if (lane == 0) { redv[w] = vs; redm[w] = ms; }
        if (lane == 1) redl[w] = lsum;
        __syncthreads();
        if (tid == 0) {
            float tot  = redl[0] + redl[1] + redl[2] + redl[3];
            float logz = cshare - KL127 + __logf(tot);
            float msum = redm[0] + redm[1] + redm[2] + redm[3];
            int last   = (int)(msum + 0.5f) - 1;
            int first  = tags[b * Tn];
            int lastt  = tags[b * Tn + last];
            float score = redv[0] + redv[1] + redv[2] + redv[3]
                        + trans[BOSs * S + first]
                        + em[((size_t)b * Tn) * S + first]
                        + trans[lastt * S + EOSs];
            atomicAdd(out, -(score - logz));
        }
    }
}

extern "C" void kernel_launch(void* const* d_in, const int* in_sizes, int n_in,
                              void* d_out, int out_size, void* d_ws, size_t ws_size,
                              hipStream_t stream) {
    const float* em    = (const float*)d_in[0];
    const int*   tags  = (const int*)d_in[1];
    const float* mask  = (const float*)d_in[2];
    const float* trans = (const float*)d_in[3];
    float* out = (float*)d_out;

    char* ws = (char*)d_ws;
    size_t off = 0;
    unsigned char* eswz = (unsigned char*)(ws + off);
    off += (size_t)ETOT;
    off = (off + 255) & ~(size_t)255;
    float* eteos = (float*)(ws + off); off += JPAD * sizeof(float);
    off = (off + 255) & ~(size_t)255;
    u64* xb = (u64*)(ws + off);        off += (size_t)2 * Bn * XSTR * sizeof(u64);

    // ws re-poisoned 0xAA pre-launch: stale tags (0xAAAAAAAA) never match t<128
    (void)hipMemsetAsync(out, 0, sizeof(float), stream);

    build_tabs<<<(ETOT + 255) / 256, 256, 0, stream>>>(trans, eswz, eteos);
    crf_fwd<<<dim3(JB, Bn), 256, 0, stream>>>(em, mask, trans, tags, eswz,
                                              eteos, xb, out);
}

// Round 9
// 319.198 us; speedup vs baseline: 1.3115x; 1.2111x over previous
//
#include <hip/hip_runtime.h>
#include <math.h>

typedef unsigned long long u64;
typedef unsigned int u32;

static constexpr int S    = 771;   // NB_LABELS*MAX_DEPTH + EXTRA
static constexpr int Tn   = 128;
static constexpr int Bn   = 32;
static constexpr int BOSs = 0;
static constexpr int EOSs = 1;

// r12 geometry (best, 295us): 7 blocks x 128 rows per batch, 224 blocks.
static constexpr int JB    = 7;            // state-blocks per batch
static constexpr int ROWS  = 128;          // output rows per block
static constexpr int JPAD  = JB * ROWS;    // 896 padded states
static constexpr int NW    = 4;            // waves per block (K-quarters)
static constexpr int KQ    = JPAD / NW;    // 224 i8 inner slice per wave
static constexpr int KW    = KQ / 4;       // 56 u32 words per quarter
static constexpr int KK    = KQ / 16;      // 14 uint4 per row-quarter
static constexpr int NDATA = JPAD / 4;     // 224 tagged data words per gen
static constexpr int NMAX  = JB * NW;      // 28 tagged per-wave max words
static constexpr int XSTR  = 256;          // u64 stride per (parity,batch)
static constexpr int EBLK  = NW * KK * 2 * 64 * 16;  // 114688 B per jblk
static constexpr int ETOT  = JB * EBLK;              // 802816 B
static constexpr float CB  = 8.0f;         // normalizer headroom (drift bound)
static constexpr float C0V = 4.5f;         // fixed normalizer for t=0 publish

__device__ __forceinline__ float wave_max_bfly(float v) {   // result in ALL lanes
    #pragma unroll
    for (int off = 32; off > 0; off >>= 1) v = fmaxf(v, __shfl_xor(v, off));
    return v;
}
__device__ __forceinline__ float wave_sum_f(float v) {
    #pragma unroll
    for (int off = 32; off > 0; off >>= 1) v += __shfl_down(v, off);
    return v;
}

__device__ __forceinline__ u64 ald64(const u64* p) {
    return __hip_atomic_load((u64*)p, __ATOMIC_RELAXED, __HIP_MEMORY_SCOPE_AGENT);
}
__device__ __forceinline__ void ast64(u64* p, u64 v) {
    __hip_atomic_store(p, v, __ATOMIC_RELAXED, __HIP_MEMORY_SCOPE_AGENT);
}
__device__ __forceinline__ u64 pack(unsigned tag, unsigned payload) {
    return ((u64)tag << 32) | (u64)payload;
}

// i8 x i8 + i32 dot (both operands in [0,127], so signed == unsigned)
#if __has_builtin(__builtin_amdgcn_sdot4)
__device__ __forceinline__ int dot4i(unsigned a, unsigned b, int c) {
    return __builtin_amdgcn_sdot4((int)a, (int)b, c, false);
}
#else
__device__ __forceinline__ int dot4i(unsigned a, unsigned b, int c) {
    c += (int)(a & 0xff)         * (int)(b & 0xff);
    c += (int)((a >> 8) & 0xff)  * (int)((b >> 8) & 0xff);
    c += (int)((a >> 16) & 0xff) * (int)((b >> 16) & 0xff);
    c += (int)((a >> 24) & 0xff) * (int)((b >> 24) & 0xff);
    return c;
}
#endif

// ---------------------------------------------------------------------------
// Prep (r12 layout, unchanged): i8 exp-transition table.
// Linear u128 index (((jb*4 + w)*14 + kk)*2 + rr)*64 + lane holds 16 i8:
//   i = w*224 + kk*16 + e      (inner state: wave w's K-quarter)
//   j = jb*128 + rr*64 + lane  (output row; lane computes rows rr=0,1)
// value = round(115*exp(trans[i][j])) in [0,127].
// ---------------------------------------------------------------------------
extern "C" __global__ void build_tabs(const float* __restrict__ trans,
                                      unsigned char* __restrict__ eswz,
                                      float* __restrict__ eteos) {
    int idx = blockIdx.x * blockDim.x + threadIdx.x;
    if (idx < JPAD)
        eteos[idx] = (idx < S) ? __expf(trans[idx * S + EOSs]) : 0.f;
    if (idx >= ETOT) return;
    int e = idx & 15;
    int u = idx >> 4;
    int lane = u & 63;  u >>= 6;
    int rr = u & 1;     u >>= 1;
    int kk = u % KK;
    int h  = u / KK;
    int w  = h & 3, jb = h >> 2;
    int i = w * KQ + kk * 16 + e;
    int j = jb * ROWS + rr * 64 + lane;
    float v = 0.f;
    if (i < S && j < S) v = 115.f * __expf(trans[i * S + j]);
    int q8 = (int)(v + 0.5f);
    if (q8 > 127) q8 = 127;
    eswz[idx] = (unsigned char)q8;
}

// per-wave publish: wave w owns rows [32w, 32w+32) of its block (af in lanes
// 0..31). 8 data u64 (word 32jb+8w+k = rows 4k..4k+3 p8-packed) + 1 max u64
// (word NDATA + 4jb + w = wave max). Tag stream IS the sync.
__device__ __forceinline__ void publishW(u64* Wp, int jb, int w, unsigned tag,
                                         float af, float C, int lane) {
    float xf = fminf(127.f, 127.f * __expf(af - C));   // -inf/-1e9 -> 0
    int xi = (int)(xf + 0.5f);
    int b0 = __shfl(xi, (4 * lane) & 63);
    int b1 = __shfl(xi, (4 * lane + 1) & 63);
    int b2 = __shfl(xi, (4 * lane + 2) & 63);
    int b3 = __shfl(xi, (4 * lane + 3) & 63);
    unsigned payload = (unsigned)b0 | ((unsigned)b1 << 8)
                     | ((unsigned)b2 << 16) | ((unsigned)b3 << 24);
    float mc = wave_max_bfly(af);                      // lanes>=32 are -inf
    if (lane < 8)  ast64(Wp + 32 * jb + 8 * w + lane, pack(tag, payload));
    if (lane == 8) ast64(Wp + NDATA + 4 * jb + w,     pack(tag, __float_as_uint(mc)));
}

// ---------------------------------------------------------------------------
// Forward algorithm, r18 = r15 (295us best) + r14 XCD co-location + s_sleep
// poll backoff.
// Evidence chain: FETCH_SIZE tracks cross-XCD probe misses (42MB for
// cross-XCD polls in r12/r15/r17; 16.6MB when co-located in r14) -> r14's
// decode DID localize the probes (fingerprint confirmed), yet ran +14%:
// local probes return ~200cy instead of ~800cy, so the un-throttled spin
// fired ~4x more probes into the SAME L2 banks where publisher stores must
// land -> store visibility queued behind the probe storm. Fix: keep the
// co-location decode, throttle the spin with s_sleep(1) (~64cy) between
// probe rounds. Probe rate drops ~5-10x; detection latency +<=64cy.
// E path: r12's plain global loads (r17 proved LDS-E is 10% SLOWER and the
// L2 remat is not on the critical path). waves_per_eu(1,1) kept from r15.
// Pre-committed: if dur ~290-340 with FETCH ~17MB, the per-step cost is
// publish-pipeline + dependent-chain irreducible -> declare latency floor.
// Mapping: id=blockIdx.x (224); xcd=id&7; slot=id>>3; jb=slot%7,
// b=xcd+8*(slot/7) -> 4 batches x 7 blocks per XCD (32 CUs each).
// Correctness is placement-independent (agent scope, per-word tags; r8
// transitivity argument unchanged).
// ---------------------------------------------------------------------------
extern "C" __global__ __attribute__((amdgpu_waves_per_eu(1, 1)))
__launch_bounds__(256)
void crf_fwd(const float* __restrict__ em, const float* __restrict__ mask,
             const float* __restrict__ trans, const int* __restrict__ tags,
             const unsigned char* __restrict__ eswz,
             const float* __restrict__ eteos,
             u64* __restrict__ xb, float* __restrict__ out) {
    const int id  = blockIdx.x;
    const int xcd = id & 7, slot = id >> 3;
    const int jb  = slot % 7;
    const int b   = xcd + 8 * (slot / 7);
    const int tid = threadIdx.x, lane = tid & 63, w = tid >> 6;

    __shared__ __align__(16) u32 strip[NW * KW];      // per-wave quarter p8
    __shared__ int   part[2][NW][ROWS];
    __shared__ float mred[2][NW];
    __shared__ float cshare;
    __shared__ float redv[NW], redm[NW], redl[NW];

    const float KLOG  = __logf(115.f * 127.f);
    const float KL127 = __logf(127.f);

    // epilogue rows of this wave: lane l<32 owns row jb*128 + 32w + l
    const int jrow = jb * ROWS + 32 * w + lane;

    // ---- t=0: publish first (unblocks everyone), then load E into regs ----
    float af = -INFINITY, Cuse = C0V;
    if (lane < 32 && jrow < S)
        af = trans[BOSs * S + jrow] + em[((size_t)b * Tn + 0) * S + jrow];
    publishW(xb + ((size_t)0 * Bn + b) * XSTR, jb, w, 0u, af, C0V, lane);

    uint4 e0[KK], e1[KK];                  // E: rows (lane, lane+64), quarter w
    {
        const uint4* src = (const uint4*)eswz
                         + ((size_t)(jb * NW + w) * KK * 2) * 64 + lane;
        #pragma unroll
        for (int kk = 0; kk < KK; ++kk) {
            e0[kk] = src[(kk * 2 + 0) * 64];
            e1[kk] = src[(kk * 2 + 1) * 64];
        }
    }
    // opaque pin (keeps the loads hoisted; allocator may still remat - ok)
    #pragma unroll
    for (int kk = 0; kk < KK; ++kk) {
        asm volatile("" : "+v"(e0[kk].x), "+v"(e0[kk].y), "+v"(e0[kk].z), "+v"(e0[kk].w));
        asm volatile("" : "+v"(e1[kk].x), "+v"(e1[kk].y), "+v"(e1[kk].z), "+v"(e1[kk].w));
    }

    const bool actd = (lane < KW);                     // 56 data-poll lanes
    const bool actm = (lane >= KW) && (lane < KW + 7); // 7 max-poll lanes

    // ---- 127 sequential steps, one barrier each ----
    for (int t = 1; t < Tn; ++t) {
        const u64* R  = xb + ((size_t)((t - 1) & 1) * Bn + b) * XSTR;
        u64*       Wp = xb + ((size_t)((t    ) & 1) * Bn + b) * XSTR;

        // epilogue operands independent of alpha: issue before the poll
        float emv = 0.f;
        if (lane < 32 && jrow < S) emv = em[((size_t)b * Tn + t) * S + jrow];
        float mval = mask[b * Tn + t];

        // ---- throttled poll: wave w waits only on its quarter's publishers
        const unsigned tg = (unsigned)(t - 1);
        const u64* pd = R + KW * w + lane;               // data word (lane<56)
        const u64* pm = R + NDATA + 7 * w + (lane - KW); // max word (7 lanes)
        u64 dc = 0, mc = 0;
        bool okd = !actd, okm = !actm;
        if (actd) dc = ald64(pd);
        if (actm) mc = ald64(pm);
        while (true) {
            if (!okd) okd = ((u32)(dc >> 32) == tg);
            if (!okm) okm = ((u32)(mc >> 32) == tg);
            if (!__any((!okd) | (!okm))) break;
            __builtin_amdgcn_s_sleep(1);    // ~64cy backoff: clears L2 ports
            if (!okd) dc = ald64(pd);
            if (!okm) mc = ald64(pm);
        }

        // ---- own strip (same-wave DS write->read: in-order, no barrier) ----
        if (actd) strip[w * KW + lane] = (u32)dc;

        // per-wave partial of next normalizer (full max after the barrier)
        float pmv = actm ? __uint_as_float((u32)mc) : -INFINITY;
        float wmax = wave_max_bfly(pmv);
        if (lane == 0) mred[t & 1][w] = wmax;

        // ---- dot: in-register E (2 rows) x quarter strip (b128 broadcast) --
        int a0 = 0, a1 = 0;
        const uint4* P4 = (const uint4*)(strip + w * KW);
        #pragma unroll
        for (int kk = 0; kk < KK; ++kk) {
            const uint4 pv = P4[kk];
            a0 = dot4i(e0[kk].x, pv.x, a0);
            a0 = dot4i(e0[kk].y, pv.y, a0);
            a0 = dot4i(e0[kk].z, pv.z, a0);
            a0 = dot4i(e0[kk].w, pv.w, a0);
            a1 = dot4i(e1[kk].x, pv.x, a1);
            a1 = dot4i(e1[kk].y, pv.y, a1);
            a1 = dot4i(e1[kk].z, pv.z, a1);
            a1 = dot4i(e1[kk].w, pv.w, a1);
        }
        part[t & 1][w][lane]      = a0;
        part[t & 1][w][64 + lane] = a1;
        __syncthreads();   // the ONLY per-step barrier

        // ---- distributed epilogue: wave w finishes rows 32w..32w+31 ----
        const int p_ = t & 1;
        const int Rr = 32 * w + (lane & 31);
        int s4 = part[p_][0][Rr] + part[p_][1][Rr]
               + part[p_][2][Rr] + part[p_][3][Rr];
        float Cnew = fmaxf(fmaxf(mred[p_][0], mred[p_][1]),
                           fmaxf(mred[p_][2], mred[p_][3])) + CB;
        float nv = Cuse - KLOG + __logf((float)s4) + emv;  // log(0) = -inf
        if (lane < 32) af = (mval > 0.f) ? nv : af;
        publishW(Wp, jb, w, (unsigned)t, af, Cnew, lane);
        Cuse = Cnew;
    }

    if (w == 0 && lane == 0) cshare = Cuse;   // C of the gen-127 publish

    // ---- tail (blocks jb==0 only): log_Z + gold score + output ----
    if (jb == 0) {
        const u64* R = xb + ((size_t)((Tn - 1) & 1) * Bn + b) * XSTR;
        const unsigned tg = (unsigned)(Tn - 1);
        const bool tact = (tid < NDATA);
        u64 qd = 0;
        bool ok = !tact;
        while (true) {
            if (!ok) { qd = ald64(R + tid); ok = ((u32)(qd >> 32) == tg); }
            if (__syncthreads_and(ok)) break;
        }
        float lsum = 0.f;
        if (tact) {
            unsigned pv = (unsigned)qd;
            int base = 4 * tid;               // p8 index j = 4*word + e
            lsum = (float)(pv & 0xff)         * eteos[base]
                 + (float)((pv >> 8)  & 0xff) * eteos[base + 1]
                 + (float)((pv >> 16) & 0xff) * eteos[base + 2]
                 + (float)((pv >> 24) & 0xff) * eteos[base + 3];
        }
        // gold-path score: thread tid<128 handles position tid
        float mk = 0.f, val = 0.f;
        if (tid < Tn) {
            mk = mask[b * Tn + tid];
            if (tid > 0) {
                int cur  = tags[b * Tn + tid];
                int prev = tags[b * Tn + tid - 1];
                val = (em[((size_t)b * Tn + tid) * S + cur]
                       + trans[prev * S + cur]) * mk;
            }
        }
        lsum = wave_sum_f(lsum);
        float vs = wave_sum_f(val);
        float ms = wave_sum_f(mk);
        if (lane == 0) { redv[w] = vs; redm[w] = ms; }
        if (lane == 1) redl[w] = lsum;
        __syncthreads();
        if (tid == 0) {
            float tot  = redl[0] + redl[1] + redl[2] + redl[3];
            float logz = cshare - KL127 + __logf(tot);
            float msum = redm[0] + redm[1] + redm[2] + redm[3];
            int last   = (int)(msum + 0.5f) - 1;
            int first  = tags[b * Tn];
            int lastt  = tags[b * Tn + last];
            float score = redv[0] + redv[1] + redv[2] + redv[3]
                        + trans[BOSs * S + first]
                        + em[((size_t)b * Tn) * S + first]
                        + trans[lastt * S + EOSs];
            atomicAdd(out, -(score - logz));
        }
    }
}

extern "C" void kernel_launch(void* const* d_in, const int* in_sizes, int n_in,
                              void* d_out, int out_size, void* d_ws, size_t ws_size,
                              hipStream_t stream) {
    const float* em    = (const float*)d_in[0];
    const int*   tags  = (const int*)d_in[1];
    const float* mask  = (const float*)d_in[2];
    const float* trans = (const float*)d_in[3];
    float* out = (float*)d_out;

    char* ws = (char*)d_ws;
    size_t off = 0;
    unsigned char* eswz = (unsigned char*)(ws + off);
    off += (size_t)ETOT;
    off = (off + 255) & ~(size_t)255;
    float* eteos = (float*)(ws + off); off += JPAD * sizeof(float);
    off = (off + 255) & ~(size_t)255;
    u64* xb = (u64*)(ws + off);        off += (size_t)2 * Bn * XSTR * sizeof(u64);

    // ws re-poisoned 0xAA pre-launch: stale tags (0xAAAAAAAA) never match t<128
    (void)hipMemsetAsync(out, 0, sizeof(float), stream);

    build_tabs<<<(ETOT + 255) / 256, 256, 0, stream>>>(trans, eswz, eteos);
    crf_fwd<<<dim3(JB * Bn), 256, 0, stream>>>(em, mask, trans, tags, eswz,
                                               eteos, xb, out);
}